// Round 9
// baseline (365.460 us; speedup 1.0000x reference)
//
#include <hip/hip_runtime.h>

#define NN 100000
#define NE 1600000
// IN_FEAT=128, N_HEADS=8, OUT_FEAT=16, H*F=128

static __device__ __forceinline__ unsigned short f32_to_bf16_rne(float x) {
    unsigned int u = __float_as_uint(x);
    u += 0x7fff + ((u >> 16) & 1);   // round-to-nearest-even
    return (unsigned short)(u >> 16);
}
static __device__ __forceinline__ float bf16_to_f32(unsigned int bits16) {
    return __uint_as_float(bits16 << 16);
}

// ---------------- Kernel 1: fused proj-GEMM + attention scores ----------------
// Outputs: projT bf16 feature-major (projT[n*128 + f*8 + h]), s_src[n*8+h], s_tgt[n*8+h].
__global__ __launch_bounds__(256) void gemm_score_kernel(const float* __restrict__ x,
                                                         const float* __restrict__ W,
                                                         const float* __restrict__ a_src,
                                                         const float* __restrict__ a_tgt,
                                                         unsigned short* __restrict__ projT,
                                                         float* __restrict__ s_src,
                                                         float* __restrict__ s_tgt) {
    __shared__ float sXT[32][68];   // k-major, padded
    __shared__ float sW[32][128];
    const int t = threadIdx.x;
    const int n0 = blockIdx.x * 64;
    const int c0 = (t & 31) * 4;    // head h=c0>>4, first feat f0=c0&15
    const int r0 = t >> 5;          // row group 0..7
    float acc[8][4];
#pragma unroll
    for (int i = 0; i < 8; i++)
#pragma unroll
        for (int j = 0; j < 4; j++) acc[i][j] = 0.f;

    for (int kt = 0; kt < 128; kt += 32) {
#pragma unroll
        for (int p = 0; p < 2; p++) {
            int idx = t + p * 256;
            int r = idx >> 3;
            int kk = idx & 7;
            float4 v = make_float4(0.f, 0.f, 0.f, 0.f);
            int n = n0 + r;
            if (n < NN) v = *reinterpret_cast<const float4*>(&x[(size_t)n * 128 + kt + kk * 4]);
            sXT[kk * 4 + 0][r] = v.x;
            sXT[kk * 4 + 1][r] = v.y;
            sXT[kk * 4 + 2][r] = v.z;
            sXT[kk * 4 + 3][r] = v.w;
        }
#pragma unroll
        for (int p = 0; p < 4; p++) {
            int idx = t + p * 256;
            int kr = idx >> 5;
            int c4 = idx & 31;
            float4 v = *reinterpret_cast<const float4*>(&W[(size_t)(kt + kr) * 128 + c4 * 4]);
            *reinterpret_cast<float4*>(&sW[kr][c4 * 4]) = v;
        }
        __syncthreads();
#pragma unroll
        for (int k = 0; k < 32; k++) {
            float4 xa = *reinterpret_cast<const float4*>(&sXT[k][r0 * 8]);
            float4 xb = *reinterpret_cast<const float4*>(&sXT[k][r0 * 8 + 4]);
            float4 wv = *reinterpret_cast<const float4*>(&sW[k][c0]);
            float xs[8] = {xa.x, xa.y, xa.z, xa.w, xb.x, xb.y, xb.z, xb.w};
#pragma unroll
            for (int i = 0; i < 8; i++) {
                acc[i][0] += xs[i] * wv.x;
                acc[i][1] += xs[i] * wv.y;
                acc[i][2] += xs[i] * wv.z;
                acc[i][3] += xs[i] * wv.w;
            }
        }
        __syncthreads();
    }
    const int h  = c0 >> 4;
    const int f0 = c0 & 15;
    const float aS0 = a_src[c0], aS1 = a_src[c0 + 1], aS2 = a_src[c0 + 2], aS3 = a_src[c0 + 3];
    const float aT0 = a_tgt[c0], aT1 = a_tgt[c0 + 1], aT2 = a_tgt[c0 + 2], aT3 = a_tgt[c0 + 3];
#pragma unroll
    for (int i = 0; i < 8; i++) {
        int n = n0 + r0 * 8 + i;
        if (n < NN) {
            unsigned short* pT = &projT[(size_t)n * 128];
#pragma unroll
            for (int j = 0; j < 4; j++) pT[(f0 + j) * 8 + h] = f32_to_bf16_rne(acc[i][j]);
            float ss = acc[i][0] * aS0 + acc[i][1] * aS1 + acc[i][2] * aS2 + acc[i][3] * aS3;
            float st = acc[i][0] * aT0 + acc[i][1] * aT1 + acc[i][2] * aT2 + acc[i][3] * aT3;
            ss += __shfl_xor(ss, 1);
            ss += __shfl_xor(ss, 2);
            st += __shfl_xor(st, 1);
            st += __shfl_xor(st, 2);
            if ((t & 3) == 0) {
                s_src[(size_t)n * 8 + h] = ss;
                s_tgt[(size_t)n * 8 + h] = st;
            }
        }
    }
}

// ---------------- CSR build: histogram -> scan -> scatter ----------------
__global__ __launch_bounds__(256) void hist_kernel(const int* __restrict__ tgt,
                                                   int* __restrict__ deg) {
    int e = blockIdx.x * blockDim.x + threadIdx.x;
    if (e >= NE) return;
    atomicAdd(&deg[tgt[e]], 1);
}

// 1024 bins per 256-thread block; per-element exclusive prefix within block + block total
__global__ __launch_bounds__(256) void scan_partial_kernel(const int* __restrict__ deg,
                                                           int* __restrict__ tmp,
                                                           int* __restrict__ blocksum) {
    __shared__ int sdata[256];
    const int b = blockIdx.x, t = threadIdx.x;
    const int base = b * 1024 + t * 4;
    int d[4], s = 0;
#pragma unroll
    for (int j = 0; j < 4; j++) {
        int i = base + j;
        d[j] = (i < NN) ? deg[i] : 0;
        s += d[j];
    }
    sdata[t] = s;
    __syncthreads();
    for (int off = 1; off < 256; off <<= 1) {
        int v = (t >= off) ? sdata[t - off] : 0;
        __syncthreads();
        sdata[t] += v;
        __syncthreads();
    }
    int excl = sdata[t] - s;   // exclusive base for this thread's 4 elems
    int run = excl;
#pragma unroll
    for (int j = 0; j < 4; j++) {
        int i = base + j;
        if (i < NN) tmp[i] = run;
        run += d[j];
    }
    if (t == 255) blocksum[b] = sdata[255];
}

#define NBLK_SCAN 98   // ceil(100000/1024)
__global__ __launch_bounds__(128) void scan_blocksums_kernel(int* __restrict__ blocksum) {
    __shared__ int sdata[128];
    const int t = threadIdx.x;
    int v = (t < NBLK_SCAN) ? blocksum[t] : 0;
    sdata[t] = v;
    __syncthreads();
    for (int off = 1; off < 128; off <<= 1) {
        int u = (t >= off) ? sdata[t - off] : 0;
        __syncthreads();
        sdata[t] += u;
        __syncthreads();
    }
    if (t < NBLK_SCAN) blocksum[t] = sdata[t] - v;   // exclusive
}

__global__ __launch_bounds__(256) void scan_finalize_kernel(const int* __restrict__ tmp,
                                                            const int* __restrict__ blocksum,
                                                            int* __restrict__ row_start,
                                                            int* __restrict__ cursor) {
    int i = blockIdx.x * blockDim.x + threadIdx.x;
    if (i >= NN) return;
    int rs = tmp[i] + blocksum[i >> 10];
    row_start[i] = rs;
    cursor[i] = rs;
}

__global__ __launch_bounds__(256) void scatter_kernel(const int* __restrict__ src,
                                                      const int* __restrict__ tgt,
                                                      int* __restrict__ cursor,
                                                      int* __restrict__ csr_src) {
    int e = blockIdx.x * blockDim.x + threadIdx.x;
    if (e >= NE) return;
    int pos = atomicAdd(&cursor[tgt[e]], 1);
    csr_src[pos] = src[e];
}

// ---------------- Fused per-target kernel: denom (regs) + weighted sum + bias + softmax ----------------
// One 16-lane group per target node. lane = feature f, h = f&7.
__global__ __launch_bounds__(256) void fused_agg_kernel(const int* __restrict__ row_start,
                                                        const int* __restrict__ deg,
                                                        const int* __restrict__ csr_src,
                                                        const float* __restrict__ s_src,
                                                        const float* __restrict__ s_tgt,
                                                        const unsigned short* __restrict__ projT,
                                                        const float* __restrict__ bias,
                                                        float* __restrict__ out) {
    int gid = blockIdx.x * blockDim.x + threadIdx.x;
    int t = gid >> 4;
    int lane = gid & 15;
    if (t >= NN) return;
    const int h = lane & 7;
    const int start = row_start[t];
    const int dg = deg[t];
    const float st = s_tgt[(size_t)t * 8 + h];

    // Phase 1: denominator in registers (lanes 0-7 even edges, 8-15 odd edges)
    float dh = 0.f;
    for (int i = (lane >> 3); i < dg; i += 2) {
        int s = csr_src[start + i];
        float v = s_src[(size_t)s * 8 + h] + st;
        v = v >= 0.f ? v : 0.2f * v;
        dh += expf(v);
    }
    dh += __shfl_xor(dh, 8, 16);
    const float inv_d = 1.f / (dh + 1e-16f);

    // Phase 2: weighted head-mean message
    float m = 0.f;
    for (int i = 0; i < dg; i++) {
        int s = csr_src[start + i];
        float eh = s_src[(size_t)s * 8 + h] + st;
        eh = eh >= 0.f ? eh : 0.2f * eh;
        float alpha = expf(eh) * inv_d;
        uint4 v = *reinterpret_cast<const uint4*>(&projT[(size_t)s * 128 + lane * 8]);
        float p0 = bf16_to_f32(v.x & 0xffffu), p1 = bf16_to_f32(v.x >> 16);
        float p2 = bf16_to_f32(v.y & 0xffffu), p3 = bf16_to_f32(v.y >> 16);
        float p4 = bf16_to_f32(v.z & 0xffffu), p5 = bf16_to_f32(v.z >> 16);
        float p6 = bf16_to_f32(v.w & 0xffffu), p7 = bf16_to_f32(v.w >> 16);
        m += __shfl(alpha, 0, 16) * p0;
        m += __shfl(alpha, 1, 16) * p1;
        m += __shfl(alpha, 2, 16) * p2;
        m += __shfl(alpha, 3, 16) * p3;
        m += __shfl(alpha, 4, 16) * p4;
        m += __shfl(alpha, 5, 16) * p5;
        m += __shfl(alpha, 6, 16) * p6;
        m += __shfl(alpha, 7, 16) * p7;
    }

    // Epilogue: bias + softmax over the 16 features held by this group
    float v = m * 0.125f + bias[lane];
    float mx = v;
#pragma unroll
    for (int mm = 1; mm < 16; mm <<= 1) mx = fmaxf(mx, __shfl_xor(mx, mm, 16));
    float ex = expf(v - mx);
    float sum = ex;
#pragma unroll
    for (int mm = 1; mm < 16; mm <<= 1) sum += __shfl_xor(sum, mm, 16);
    out[(size_t)t * 16 + lane] = ex / sum;
}

extern "C" void kernel_launch(void* const* d_in, const int* in_sizes, int n_in,
                              void* d_out, int out_size, void* d_ws, size_t ws_size,
                              hipStream_t stream) {
    const float* x     = (const float*)d_in[0];
    const int*   ei    = (const int*)d_in[1];
    const float* W     = (const float*)d_in[2];
    const float* a_src = (const float*)d_in[3];
    const float* a_tgt = (const float*)d_in[4];
    const float* bias  = (const float*)d_in[5];
    float* out = (float*)d_out;

    const int* src = ei;            // edge_index[0]
    const int* tgt = ei + NE;       // edge_index[1]

    char* ws = (char*)d_ws;
    size_t off = 0;
    auto alloc = [&](size_t bytes) {
        char* p = ws + off;
        off += (bytes + 255) & ~(size_t)255;
        return p;
    };
    unsigned short* projT     = (unsigned short*)alloc((size_t)NN * 128 * 2); // 25.6 MB
    float*          s_src     = (float*)alloc((size_t)NN * 8 * 4);            // 3.2 MB
    float*          s_tgt     = (float*)alloc((size_t)NN * 8 * 4);            // 3.2 MB
    int*            deg       = (int*)alloc((size_t)NN * 4);
    int*            tmp       = (int*)alloc((size_t)NN * 4);
    int*            blocksum  = (int*)alloc((size_t)NBLK_SCAN * 4);
    int*            row_start = (int*)alloc((size_t)NN * 4);
    int*            cursor    = (int*)alloc((size_t)NN * 4);
    int*            csr_src   = (int*)alloc((size_t)NE * 4);                  // 6.4 MB

    hipMemsetAsync(deg, 0, (size_t)NN * 4, stream);

    gemm_score_kernel<<<(NN + 63) / 64, 256, 0, stream>>>(x, W, a_src, a_tgt, projT, s_src, s_tgt);
    hist_kernel<<<(NE + 255) / 256, 256, 0, stream>>>(tgt, deg);
    scan_partial_kernel<<<NBLK_SCAN, 256, 0, stream>>>(deg, tmp, blocksum);
    scan_blocksums_kernel<<<1, 128, 0, stream>>>(blocksum);
    scan_finalize_kernel<<<(NN + 255) / 256, 256, 0, stream>>>(tmp, blocksum, row_start, cursor);
    scatter_kernel<<<(NE + 255) / 256, 256, 0, stream>>>(src, tgt, cursor, csr_src);
    fused_agg_kernel<<<((size_t)NN * 16 + 255) / 256, 256, 0, stream>>>(row_start, deg, csr_src,
                                                                        s_src, s_tgt, projT, bias, out);
}

// Round 10
// 256.838 us; speedup vs baseline: 1.4229x; 1.4229x over previous
//
#include <hip/hip_runtime.h>

#define NN 100000
#define NE 1600000
// IN_FEAT=128, N_HEADS=8, OUT_FEAT=16, H*F=128

static __device__ __forceinline__ unsigned short f32_to_bf16_rne(float x) {
    unsigned int u = __float_as_uint(x);
    u += 0x7fff + ((u >> 16) & 1);   // round-to-nearest-even
    return (unsigned short)(u >> 16);
}
static __device__ __forceinline__ float bf16_to_f32(unsigned int bits16) {
    return __uint_as_float(bits16 << 16);
}

// ---------------- Kernel 1: fused proj-GEMM + attention scores ----------------
// Outputs: projT bf16 feature-major (projT[n*128 + f*8 + h]),
//          s_src[n*8+h] (f32), pack[n*16+h] = s_tgt ; pack[n*16+8+h] = denom (zeroed, filled by denom pass).
__global__ __launch_bounds__(256) void gemm_score_kernel(const float* __restrict__ x,
                                                         const float* __restrict__ W,
                                                         const float* __restrict__ a_src,
                                                         const float* __restrict__ a_tgt,
                                                         unsigned short* __restrict__ projT,
                                                         float* __restrict__ s_src,
                                                         float* __restrict__ pack) {
    __shared__ float sXT[32][68];   // k-major, padded
    __shared__ float sW[32][128];
    const int t = threadIdx.x;
    const int n0 = blockIdx.x * 64;
    const int c0 = (t & 31) * 4;    // head h=c0>>4, first feat f0=c0&15
    const int r0 = t >> 5;          // row group 0..7
    float acc[8][4];
#pragma unroll
    for (int i = 0; i < 8; i++)
#pragma unroll
        for (int j = 0; j < 4; j++) acc[i][j] = 0.f;

    for (int kt = 0; kt < 128; kt += 32) {
#pragma unroll
        for (int p = 0; p < 2; p++) {
            int idx = t + p * 256;
            int r = idx >> 3;
            int kk = idx & 7;
            float4 v = make_float4(0.f, 0.f, 0.f, 0.f);
            int n = n0 + r;
            if (n < NN) v = *reinterpret_cast<const float4*>(&x[(size_t)n * 128 + kt + kk * 4]);
            sXT[kk * 4 + 0][r] = v.x;
            sXT[kk * 4 + 1][r] = v.y;
            sXT[kk * 4 + 2][r] = v.z;
            sXT[kk * 4 + 3][r] = v.w;
        }
#pragma unroll
        for (int p = 0; p < 4; p++) {
            int idx = t + p * 256;
            int kr = idx >> 5;
            int c4 = idx & 31;
            float4 v = *reinterpret_cast<const float4*>(&W[(size_t)(kt + kr) * 128 + c4 * 4]);
            *reinterpret_cast<float4*>(&sW[kr][c4 * 4]) = v;
        }
        __syncthreads();
#pragma unroll
        for (int k = 0; k < 32; k++) {
            float4 xa = *reinterpret_cast<const float4*>(&sXT[k][r0 * 8]);
            float4 xb = *reinterpret_cast<const float4*>(&sXT[k][r0 * 8 + 4]);
            float4 wv = *reinterpret_cast<const float4*>(&sW[k][c0]);
            float xs[8] = {xa.x, xa.y, xa.z, xa.w, xb.x, xb.y, xb.z, xb.w};
#pragma unroll
            for (int i = 0; i < 8; i++) {
                acc[i][0] += xs[i] * wv.x;
                acc[i][1] += xs[i] * wv.y;
                acc[i][2] += xs[i] * wv.z;
                acc[i][3] += xs[i] * wv.w;
            }
        }
        __syncthreads();
    }
    const int h  = c0 >> 4;
    const int f0 = c0 & 15;
    const float aS0 = a_src[c0], aS1 = a_src[c0 + 1], aS2 = a_src[c0 + 2], aS3 = a_src[c0 + 3];
    const float aT0 = a_tgt[c0], aT1 = a_tgt[c0 + 1], aT2 = a_tgt[c0 + 2], aT3 = a_tgt[c0 + 3];
#pragma unroll
    for (int i = 0; i < 8; i++) {
        int n = n0 + r0 * 8 + i;
        if (n < NN) {
            unsigned short* pT = &projT[(size_t)n * 128];
#pragma unroll
            for (int j = 0; j < 4; j++) pT[(f0 + j) * 8 + h] = f32_to_bf16_rne(acc[i][j]);
            float ss = acc[i][0] * aS0 + acc[i][1] * aS1 + acc[i][2] * aS2 + acc[i][3] * aS3;
            float st = acc[i][0] * aT0 + acc[i][1] * aT1 + acc[i][2] * aT2 + acc[i][3] * aT3;
            ss += __shfl_xor(ss, 1);
            ss += __shfl_xor(ss, 2);
            st += __shfl_xor(st, 1);
            st += __shfl_xor(st, 2);
            if ((t & 3) == 0) {
                s_src[(size_t)n * 8 + h] = ss;
                pack[(size_t)n * 16 + h] = st;   // s_tgt half of the packed line
            }
        }
    }
}

// ---------------- Kernel 2: per-(edge,head) exp(leaky) -> denom + store ex (bf16) ----------------
// One lane per (edge, head); 8 consecutive lanes -> consecutive addresses (coalesced atomic + store).
// ex stored bf16 so the aggregate pass needs no scattered score reads and no exp recompute.
__global__ __launch_bounds__(256) void denom_kernel(const int* __restrict__ src,
                                                    const int* __restrict__ tgt,
                                                    const float* __restrict__ s_src,
                                                    float* __restrict__ pack,
                                                    unsigned short* __restrict__ exb) {
    int gid = blockIdx.x * blockDim.x + threadIdx.x;
    int e = gid >> 3;
    if (e >= NE) return;
    int h = gid & 7;
    int s = src[e], t = tgt[e];
    float v = s_src[(size_t)s * 8 + h] + pack[(size_t)t * 16 + h];
    v = v >= 0.f ? v : 0.2f * v;
    float ex = expf(v);
    exb[(size_t)e * 8 + h] = f32_to_bf16_rne(ex);
    atomicAdd(&pack[(size_t)t * 16 + 8 + h], ex);
}

// ---------------- Kernel 3: per-edge alpha from stored ex, head-reduced message, scatter-add ----------------
__global__ __launch_bounds__(256) void aggregate_kernel(const int* __restrict__ src,
                                                        const int* __restrict__ tgt,
                                                        const float* __restrict__ pack,
                                                        const unsigned short* __restrict__ exb,
                                                        const unsigned short* __restrict__ projT,
                                                        float* __restrict__ out_acc) {
    int gid = blockIdx.x * blockDim.x + threadIdx.x;
    int e = gid >> 4;
    int lane = gid & 15;   // output feature f
    if (e >= NE) return;
    int s = src[e], t = tgt[e];
    int h = lane & 7;
    float ex = bf16_to_f32(exb[(size_t)e * 8 + h]);
    float alpha = ex / (pack[(size_t)t * 16 + 8 + h] + 1e-16f);
    // gather 8 heads at feature 'lane': 16 bytes
    uint4 v = *reinterpret_cast<const uint4*>(&projT[(size_t)s * 128 + lane * 8]);
    float p0 = bf16_to_f32(v.x & 0xffffu), p1 = bf16_to_f32(v.x >> 16);
    float p2 = bf16_to_f32(v.y & 0xffffu), p3 = bf16_to_f32(v.y >> 16);
    float p4 = bf16_to_f32(v.z & 0xffffu), p5 = bf16_to_f32(v.z >> 16);
    float p6 = bf16_to_f32(v.w & 0xffffu), p7 = bf16_to_f32(v.w >> 16);
    float m = 0.f;
    m += __shfl(alpha, 0, 16) * p0;
    m += __shfl(alpha, 1, 16) * p1;
    m += __shfl(alpha, 2, 16) * p2;
    m += __shfl(alpha, 3, 16) * p3;
    m += __shfl(alpha, 4, 16) * p4;
    m += __shfl(alpha, 5, 16) * p5;
    m += __shfl(alpha, 6, 16) * p6;
    m += __shfl(alpha, 7, 16) * p7;
    atomicAdd(&out_acc[(size_t)t * 16 + lane], m * 0.125f);
}

// ---------------- Kernel 4: bias + softmax over 16 features ----------------
__global__ __launch_bounds__(256) void softmax_kernel(const float* __restrict__ out_acc,
                                                      const float* __restrict__ bias,
                                                      float* __restrict__ out) {
    int gid = blockIdx.x * blockDim.x + threadIdx.x;
    int n = gid >> 4;
    int lane = gid & 15;
    if (n >= NN) return;
    float v = out_acc[(size_t)n * 16 + lane] + bias[lane];
    float mx = v;
#pragma unroll
    for (int m = 1; m < 16; m <<= 1) mx = fmaxf(mx, __shfl_xor(mx, m, 64));
    float ex = expf(v - mx);
    float sum = ex;
#pragma unroll
    for (int m = 1; m < 16; m <<= 1) sum += __shfl_xor(sum, m, 64);
    out[(size_t)n * 16 + lane] = ex / sum;
}

extern "C" void kernel_launch(void* const* d_in, const int* in_sizes, int n_in,
                              void* d_out, int out_size, void* d_ws, size_t ws_size,
                              hipStream_t stream) {
    const float* x     = (const float*)d_in[0];
    const int*   ei    = (const int*)d_in[1];
    const float* W     = (const float*)d_in[2];
    const float* a_src = (const float*)d_in[3];
    const float* a_tgt = (const float*)d_in[4];
    const float* bias  = (const float*)d_in[5];
    float* out = (float*)d_out;

    const int* src = ei;            // edge_index[0]
    const int* tgt = ei + NE;       // edge_index[1]

    char* ws = (char*)d_ws;
    size_t off = 0;
    auto alloc = [&](size_t bytes) {
        char* p = ws + off;
        off += (bytes + 255) & ~(size_t)255;
        return p;
    };
    unsigned short* projT   = (unsigned short*)alloc((size_t)NN * 128 * 2); // 25.6 MB bf16, f-major
    unsigned short* exb     = (unsigned short*)alloc((size_t)NE * 8 * 2);   // 25.6 MB bf16 ex[e][h]
    float*          s_src   = (float*)alloc((size_t)NN * 8 * 4);            // 3.2 MB
    float*          pack    = (float*)alloc((size_t)NN * 16 * 4);           // 6.4 MB: [0..7]=s_tgt, [8..15]=denom
    float*          out_acc = (float*)alloc((size_t)NN * 16 * 4);           // 6.4 MB

    // zero accumulators every call (harness does not re-poison between replays)
    hipMemsetAsync(pack, 0, (size_t)NN * 16 * 4, stream);
    hipMemsetAsync(out_acc, 0, (size_t)NN * 16 * 4, stream);

    gemm_score_kernel<<<(NN + 63) / 64, 256, 0, stream>>>(x, W, a_src, a_tgt, projT, s_src, pack);
    denom_kernel<<<((size_t)NE * 8 + 255) / 256, 256, 0, stream>>>(src, tgt, s_src, pack, exb);
    aggregate_kernel<<<((size_t)NE * 16 + 255) / 256, 256, 0, stream>>>(src, tgt, pack, exb,
                                                                        projT, out_acc);
    softmax_kernel<<<(NN * 16 + 255) / 256, 256, 0, stream>>>(out_acc, bias, out);
}

// Round 13
// 247.666 us; speedup vs baseline: 1.4756x; 1.0370x over previous
//
#include <hip/hip_runtime.h>

#define NN 100000
#define NE 1600000
// IN_FEAT=128, N_HEADS=8, OUT_FEAT=16, H*F=128

static __device__ __forceinline__ unsigned short f32_to_bf16_rne(float x) {
    unsigned int u = __float_as_uint(x);
    u += 0x7fff + ((u >> 16) & 1);   // round-to-nearest-even
    return (unsigned short)(u >> 16);
}
static __device__ __forceinline__ float bf16_to_f32(unsigned int bits16) {
    return __uint_as_float(bits16 << 16);
}

// ---------------- Kernel 1: fused proj-GEMM + attention scores ----------------
// Outputs: projT bf16 feature-major (projT[n*128 + f*8 + h]),
//          s_src_b / s_tgt_b bf16 [N,8] (hot gather arrays, 1.6 MB each).
__global__ __launch_bounds__(256) void gemm_score_kernel(const float* __restrict__ x,
                                                         const float* __restrict__ W,
                                                         const float* __restrict__ a_src,
                                                         const float* __restrict__ a_tgt,
                                                         unsigned short* __restrict__ projT,
                                                         unsigned short* __restrict__ s_src_b,
                                                         unsigned short* __restrict__ s_tgt_b) {
    __shared__ float sXT[32][68];   // k-major, padded
    __shared__ float sW[32][128];
    const int t = threadIdx.x;
    const int n0 = blockIdx.x * 64;
    const int c0 = (t & 31) * 4;    // head h=c0>>4, first feat f0=c0&15
    const int r0 = t >> 5;          // row group 0..7
    float acc[8][4];
#pragma unroll
    for (int i = 0; i < 8; i++)
#pragma unroll
        for (int j = 0; j < 4; j++) acc[i][j] = 0.f;

    for (int kt = 0; kt < 128; kt += 32) {
#pragma unroll
        for (int p = 0; p < 2; p++) {
            int idx = t + p * 256;
            int r = idx >> 3;
            int kk = idx & 7;
            float4 v = make_float4(0.f, 0.f, 0.f, 0.f);
            int n = n0 + r;
            if (n < NN) v = *reinterpret_cast<const float4*>(&x[(size_t)n * 128 + kt + kk * 4]);
            sXT[kk * 4 + 0][r] = v.x;
            sXT[kk * 4 + 1][r] = v.y;
            sXT[kk * 4 + 2][r] = v.z;
            sXT[kk * 4 + 3][r] = v.w;
        }
#pragma unroll
        for (int p = 0; p < 4; p++) {
            int idx = t + p * 256;
            int kr = idx >> 5;
            int c4 = idx & 31;
            float4 v = *reinterpret_cast<const float4*>(&W[(size_t)(kt + kr) * 128 + c4 * 4]);
            *reinterpret_cast<float4*>(&sW[kr][c4 * 4]) = v;
        }
        __syncthreads();
#pragma unroll
        for (int k = 0; k < 32; k++) {
            float4 xa = *reinterpret_cast<const float4*>(&sXT[k][r0 * 8]);
            float4 xb = *reinterpret_cast<const float4*>(&sXT[k][r0 * 8 + 4]);
            float4 wv = *reinterpret_cast<const float4*>(&sW[k][c0]);
            float xs[8] = {xa.x, xa.y, xa.z, xa.w, xb.x, xb.y, xb.z, xb.w};
#pragma unroll
            for (int i = 0; i < 8; i++) {
                acc[i][0] += xs[i] * wv.x;
                acc[i][1] += xs[i] * wv.y;
                acc[i][2] += xs[i] * wv.z;
                acc[i][3] += xs[i] * wv.w;
            }
        }
        __syncthreads();
    }
    const int h  = c0 >> 4;
    const int f0 = c0 & 15;
    const float aS0 = a_src[c0], aS1 = a_src[c0 + 1], aS2 = a_src[c0 + 2], aS3 = a_src[c0 + 3];
    const float aT0 = a_tgt[c0], aT1 = a_tgt[c0 + 1], aT2 = a_tgt[c0 + 2], aT3 = a_tgt[c0 + 3];
#pragma unroll
    for (int i = 0; i < 8; i++) {
        int n = n0 + r0 * 8 + i;
        if (n < NN) {
            unsigned short* pT = &projT[(size_t)n * 128];
#pragma unroll
            for (int j = 0; j < 4; j++) pT[(f0 + j) * 8 + h] = f32_to_bf16_rne(acc[i][j]);
            float ss = acc[i][0] * aS0 + acc[i][1] * aS1 + acc[i][2] * aS2 + acc[i][3] * aS3;
            float st = acc[i][0] * aT0 + acc[i][1] * aT1 + acc[i][2] * aT2 + acc[i][3] * aT3;
            ss += __shfl_xor(ss, 1);
            ss += __shfl_xor(ss, 2);
            st += __shfl_xor(st, 1);
            st += __shfl_xor(st, 2);
            if ((t & 3) == 0) {
                s_src_b[(size_t)n * 8 + h] = f32_to_bf16_rne(ss);
                s_tgt_b[(size_t)n * 8 + h] = f32_to_bf16_rne(st);
            }
        }
    }
}

// ---------------- Kernel 2: per-(edge,head) exp(leaky) -> denom + store ex (bf16) ----------------
// bf16 score arrays shrink the hot random-gather set (3.2 MB scores + 3.2 MB denom)
// toward per-XCD L2 capacity. Numerator ex (exb) and denominator use the SAME
// bf16-rounded score, so the rounding largely cancels in alpha.
__global__ __launch_bounds__(256) void denom_kernel(const int* __restrict__ src,
                                                    const int* __restrict__ tgt,
                                                    const unsigned short* __restrict__ s_src_b,
                                                    const unsigned short* __restrict__ s_tgt_b,
                                                    float* __restrict__ denom,
                                                    unsigned short* __restrict__ exb) {
    int gid = blockIdx.x * blockDim.x + threadIdx.x;
    int e = gid >> 3;
    if (e >= NE) return;
    int h = gid & 7;
    int s = src[e], t = tgt[e];
    float v = bf16_to_f32(s_src_b[(size_t)s * 8 + h]) + bf16_to_f32(s_tgt_b[(size_t)t * 8 + h]);
    v = v >= 0.f ? v : 0.2f * v;
    float ex = expf(v);
    exb[(size_t)e * 8 + h] = f32_to_bf16_rne(ex);
    atomicAdd(&denom[(size_t)t * 8 + h], ex);
}

// ---------------- Kernel 3: per-edge alpha from stored ex, head-reduced message, scatter-add ----------------
__global__ __launch_bounds__(256) void aggregate_kernel(const int* __restrict__ src,
                                                        const int* __restrict__ tgt,
                                                        const float* __restrict__ denom,
                                                        const unsigned short* __restrict__ exb,
                                                        const unsigned short* __restrict__ projT,
                                                        float* __restrict__ out_acc) {
    int gid = blockIdx.x * blockDim.x + threadIdx.x;
    int e = gid >> 4;
    int lane = gid & 15;   // output feature f
    if (e >= NE) return;
    int s = src[e], t = tgt[e];
    int h = lane & 7;
    float ex = bf16_to_f32(exb[(size_t)e * 8 + h]);
    float alpha = ex / (denom[(size_t)t * 8 + h] + 1e-16f);
    // gather 8 heads at feature 'lane': 16 bytes
    uint4 v = *reinterpret_cast<const uint4*>(&projT[(size_t)s * 128 + lane * 8]);
    float p0 = bf16_to_f32(v.x & 0xffffu), p1 = bf16_to_f32(v.x >> 16);
    float p2 = bf16_to_f32(v.y & 0xffffu), p3 = bf16_to_f32(v.y >> 16);
    float p4 = bf16_to_f32(v.z & 0xffffu), p5 = bf16_to_f32(v.z >> 16);
    float p6 = bf16_to_f32(v.w & 0xffffu), p7 = bf16_to_f32(v.w >> 16);
    float m = 0.f;
    m += __shfl(alpha, 0, 16) * p0;
    m += __shfl(alpha, 1, 16) * p1;
    m += __shfl(alpha, 2, 16) * p2;
    m += __shfl(alpha, 3, 16) * p3;
    m += __shfl(alpha, 4, 16) * p4;
    m += __shfl(alpha, 5, 16) * p5;
    m += __shfl(alpha, 6, 16) * p6;
    m += __shfl(alpha, 7, 16) * p7;
    atomicAdd(&out_acc[(size_t)t * 16 + lane], m * 0.125f);
}

// ---------------- Kernel 4: bias + softmax over 16 features ----------------
__global__ __launch_bounds__(256) void softmax_kernel(const float* __restrict__ out_acc,
                                                      const float* __restrict__ bias,
                                                      float* __restrict__ out) {
    int gid = blockIdx.x * blockDim.x + threadIdx.x;
    int n = gid >> 4;
    int lane = gid & 15;
    if (n >= NN) return;
    float v = out_acc[(size_t)n * 16 + lane] + bias[lane];
    float mx = v;
#pragma unroll
    for (int m = 1; m < 16; m <<= 1) mx = fmaxf(mx, __shfl_xor(mx, m, 64));
    float ex = expf(v - mx);
    float sum = ex;
#pragma unroll
    for (int m = 1; m < 16; m <<= 1) sum += __shfl_xor(sum, m, 64);
    out[(size_t)n * 16 + lane] = ex / sum;
}

extern "C" void kernel_launch(void* const* d_in, const int* in_sizes, int n_in,
                              void* d_out, int out_size, void* d_ws, size_t ws_size,
                              hipStream_t stream) {
    const float* x     = (const float*)d_in[0];
    const int*   ei    = (const int*)d_in[1];
    const float* W     = (const float*)d_in[2];
    const float* a_src = (const float*)d_in[3];
    const float* a_tgt = (const float*)d_in[4];
    const float* bias  = (const float*)d_in[5];
    float* out = (float*)d_out;

    const int* src = ei;            // edge_index[0]
    const int* tgt = ei + NE;       // edge_index[1]

    char* ws = (char*)d_ws;
    size_t off = 0;
    auto alloc = [&](size_t bytes) {
        char* p = ws + off;
        off += (bytes + 255) & ~(size_t)255;
        return p;
    };
    unsigned short* projT   = (unsigned short*)alloc((size_t)NN * 128 * 2); // 25.6 MB bf16, f-major
    unsigned short* exb     = (unsigned short*)alloc((size_t)NE * 8 * 2);   // 25.6 MB bf16 ex[e][h]
    unsigned short* s_src_b = (unsigned short*)alloc((size_t)NN * 8 * 2);   // 1.6 MB
    unsigned short* s_tgt_b = (unsigned short*)alloc((size_t)NN * 8 * 2);   // 1.6 MB
    float*          denom   = (float*)alloc((size_t)NN * 8 * 4);            // 3.2 MB
    float*          out_acc = (float*)alloc((size_t)NN * 16 * 4);           // 6.4 MB

    // zero accumulators every call (harness does not re-poison between replays)
    hipMemsetAsync(denom, 0, (size_t)NN * 8 * 4, stream);
    hipMemsetAsync(out_acc, 0, (size_t)NN * 16 * 4, stream);

    gemm_score_kernel<<<(NN + 63) / 64, 256, 0, stream>>>(x, W, a_src, a_tgt, projT, s_src_b, s_tgt_b);
    denom_kernel<<<((size_t)NE * 8 + 255) / 256, 256, 0, stream>>>(src, tgt, s_src_b, s_tgt_b, denom, exb);
    aggregate_kernel<<<((size_t)NE * 16 + 255) / 256, 256, 0, stream>>>(src, tgt, denom, exb,
                                                                        projT, out_acc);
    softmax_kernel<<<(NN * 16 + 255) / 256, 256, 0, stream>>>(out_acc, bias, out);
}